// Round 6
// baseline (162.148 us; speedup 1.0000x reference)
//
#include <hip/hip_runtime.h>
#include <hip/hip_bf16.h>

// LSTM cell fused kernel for MI355X (gfx950) — round 6: flatmm-style.
// B (weights) streamed DIRECT global->VGPR from a fragment-ordered layout;
// only A goes through LDS. stacked = [x|prevh]@[Wx;Wh]+bx -> gates -> h,c.
// GEMM: M=8192, N=4096 (4 gates x 1024 states), K=2048, bf16 16x16x32 MFMA.
//
// Rationale (rounds 1-5 post-mortem): every schedule variant pinned at
// ~780 TF / 6,640 cyc per 256^2-tile vs ~3,100-cyc LDS floor — LDS traffic
// (A x4 + B x2 read amplification + stage writes = 256 KB/tile) and the
// barrier-coupled read path are the shared invariant. This round removes
// B from LDS: traffic 256->160 KB/tile, B latency hidden by per-wave
// vmcnt scoreboard (no barriers), 1 barrier/tile.
//
// Wt2 layout (built by convW2): for (nt, wc, kt):  8 KB contiguous =
//   [g:4][kf:2][lane:64][e:8] bf16, value = W[k][n],
//   k = kt*64 + kf*32 + (lane>>4)*8 + e,  n = g*1024 + nt*64 + wc*16 + (lane&15)
// -> wave (nt,wc) at K-tile kt loads 8 x 1KB fully-coalesced dwordx4.
//
// A path (unchanged, verified 0 bank conflicts): 4-slot LDS ring of 16 KB
// halves (slot 2*(t&1)+p), T2 both-sides XOR swizzle, gload_lds width 16.
// Per-tile: top issues {bfNXT(t+1) 8 reg-loads, SA(t+1) 4 gloads}; 4 chunked
// af reads with counted lgkm; 4 MFMA bursts; end vmcnt(0) (all outstanding
// loads are >= 1 tile old => cheap) + ONE barrier.
// Ring WAR: SA(t+1)@top-of-t writes parity ~t slots; tile t-1 readers done
// before end-barrier(t-1) which precedes the issue. Safe.
//
// ws layout: A_bf16 [8192][2048] (32MB) | Wt2 (16MB)

#define BATCH   8192
#define SDIM    1024
#define KDIM    2048
#define NT      32      // K-tiles of 64

typedef __attribute__((ext_vector_type(8))) short s16x8;
typedef __attribute__((ext_vector_type(4))) float f32x4;

__device__ __forceinline__ void gload16(const void* g, void* l) {
    __builtin_amdgcn_global_load_lds((const __attribute__((address_space(1))) void*)g,
                                     (__attribute__((address_space(3))) void*)l,
                                     16, 0, 0);
}

__device__ __forceinline__ float fast_sigmoid(float x) {
    return 1.0f / (1.0f + __expf(-x));
}
__device__ __forceinline__ float fast_tanh(float v) {
    float a = fabsf(v);
    float e = __expf(-2.0f * a);
    float t = (1.0f - e) / (1.0f + e);
    return copysignf(t, v);
}

// ---------------- conversion: A = [x | prevh] -> bf16 [8192][2048] ----------
__global__ void convA(const float* __restrict__ x, const float* __restrict__ h,
                      __hip_bfloat16* __restrict__ A) {
    int t = blockIdx.x * blockDim.x + threadIdx.x;
    int e = t << 3;
    int b = e >> 11;
    int k = e & 2047;
    const float* src = (k < 1024) ? (x + (size_t)b * 1024 + k)
                                  : (h + (size_t)b * 1024 + (k - 1024));
    float4 v0 = *(const float4*)(src);
    float4 v1 = *(const float4*)(src + 4);
    union { __hip_bfloat16 b[8]; s16x8 v; } u;
    u.b[0] = __float2bfloat16(v0.x); u.b[1] = __float2bfloat16(v0.y);
    u.b[2] = __float2bfloat16(v0.z); u.b[3] = __float2bfloat16(v0.w);
    u.b[4] = __float2bfloat16(v1.x); u.b[5] = __float2bfloat16(v1.y);
    u.b[6] = __float2bfloat16(v1.z); u.b[7] = __float2bfloat16(v1.w);
    *(s16x8*)(A + e) = u.v;
}

// ---- conversion to fragment-ordered Wt2 ------------------------------------
// One thread per 16B output. tid decomposition matches the layout comment.
__global__ void convW2(const float* __restrict__ Wx, const float* __restrict__ Wh,
                       __hip_bfloat16* __restrict__ Wt2) {
    int tid  = blockIdx.x * blockDim.x + threadIdx.x;   // 1,048,576
    int lane = tid & 63;
    int r    = tid >> 6;
    int kfg  = r & 7;          // g*2+kf
    int g    = kfg >> 1;
    int kf   = kfg & 1;
    int r2   = r >> 3;
    int kt   = r2 & 31;
    int r3   = r2 >> 5;
    int wc   = r3 & 3;
    int ntl  = r3 >> 2;        // 0..15
    int n     = g * 1024 + ntl * 64 + wc * 16 + (lane & 15);
    int kbase = kt * 64 + kf * 32 + (lane >> 4) * 8;
    const float* src = (kbase < 1024) ? (Wx + (size_t)kbase * 4096 + n)
                                      : (Wh + (size_t)(kbase - 1024) * 4096 + n);
    union { __hip_bfloat16 b[8]; s16x8 v; } u;
#pragma unroll
    for (int e = 0; e < 8; ++e)
        u.b[e] = __float2bfloat16(src[(size_t)e * 4096]);
    *(s16x8*)((char*)Wt2 + (size_t)tid * 16) = u.v;
}

// ---------------- fused GEMM + gates ----------------------------------------
__global__ __launch_bounds__(512, 2) void lstm_gemm(
    const __hip_bfloat16* __restrict__ A,    // [8192][2048]
    const __hip_bfloat16* __restrict__ Wt2,  // fragment-ordered (16MB)
    const float* __restrict__ bx,            // [4096]
    const float* __restrict__ prevc,         // [8192][1024]
    float* __restrict__ outh,
    float* __restrict__ outc)
{
    // A ring only: 4 slots x 16 KB
    __shared__ __align__(16) char lds[65536];

    const int tid  = threadIdx.x;
    const int lane = tid & 63;
    const int w    = tid >> 6;   // 0..7
    const int wr   = w >> 2;     // 0..1  A-half
    const int wc   = w & 3;      // 0..3  N quarter
    const int l15  = lane & 15;

    // XCD chunking (unchanged, FETCH-verified): 8 chunks of 8Mt x 8Nt.
    const int bid = blockIdx.x;
    const int xcd = bid & 7, j = bid >> 3;
    const int mt = (xcd >> 1) * 8 + (j & 7);     // 0..31
    const int nt = (xcd & 1) * 8 + (j >> 3);     // 0..15
    const int m0 = mt * 256, S0 = nt * 64;

    // A staging: linear gload_lds dest, inverse-swizzled global source.
    const int scol = ((lane & 7) ^ (lane >> 3)) << 3;   // elems
    const __hip_bfloat16* Ag = A + (size_t)m0 * KDIM;

    auto SA = [&](int tt, int p) {
        char* dst = lds + (2 * (tt & 1) + p) * 16384 + w * 1024;
        const __hip_bfloat16* src =
            Ag + (size_t)(p * 128 + w * 8 + (lane >> 3)) * KDIM + tt * 64 + scol;
        gload16(src, dst);
        gload16(src + (size_t)64 * KDIM, dst + 8192);
    };

    // B fragment stream base for this wave: (nt*4+wc) chunk, 8KB per K-tile.
    const char* wb = (const char*)Wt2 + ((size_t)(nt * 4 + wc) * 32) * 8192
                   + (size_t)lane * 16;

    f32x4 acc[8][4];
#pragma unroll
    for (int m = 0; m < 8; ++m)
#pragma unroll
        for (int g = 0; g < 4; ++g)
            acc[m][g] = (f32x4)0.0f;

    s16x8 bfA[4][2], bfB[4][2];
    s16x8 afX[2][2], afY[2][2];

#define LOADB(BF, T)                                                      \
    _Pragma("unroll")                                                     \
    for (int g = 0; g < 4; ++g)                                           \
        _Pragma("unroll")                                                 \
        for (int kf = 0; kf < 2; ++kf)                                    \
            BF[g][kf] = *(const s16x8*)(wb + (size_t)(T) * 8192           \
                                           + (g * 2 + kf) * 1024);

    // prologue: SA(0) then bfA(0); vmcnt(8) -> SA(0) landed, bfA in flight
    SA(0, 0); SA(0, 1);
    LOADB(bfA, 0);
    asm volatile("s_waitcnt vmcnt(8)" ::: "memory");
    __builtin_amdgcn_s_barrier();
    __builtin_amdgcn_sched_barrier(0);

    // read-side swizzle (verified 0 conflicts)
    const int swz0 = (((lane >> 4))     ^ (lane & 7)) << 4;
    const int swz1 = (((lane >> 4) | 4) ^ (lane & 7)) << 4;

#define LGKM(n)                                             \
    asm volatile("s_waitcnt lgkmcnt(" #n ")" ::: "memory"); \
    __builtin_amdgcn_sched_barrier(0);

#define RD2(AF, r0)                                                           \
    _Pragma("unroll")                                                         \
    for (int mm = 0; mm < 2; ++mm) {                                          \
        AF[mm][0] = *(const s16x8*)(as + (((r0) + mm) * 16 + l15) * 128 + swz0);\
        AF[mm][1] = *(const s16x8*)(as + (((r0) + mm) * 16 + l15) * 128 + swz1);\
    }

#define MB(AF, BF, mb)                                                        \
    __builtin_amdgcn_s_setprio(1);                                            \
    _Pragma("unroll")                                                         \
    for (int kf = 0; kf < 2; ++kf)                                            \
        _Pragma("unroll")                                                     \
        for (int mm = 0; mm < 2; ++mm)                                        \
            _Pragma("unroll")                                                 \
            for (int g = 0; g < 4; ++g)                                       \
                acc[(mb) + mm][g] = __builtin_amdgcn_mfma_f32_16x16x32_bf16(  \
                    AF[mm][kf], BF[g][kf], acc[(mb) + mm][g], 0, 0, 0);       \
    __builtin_amdgcn_s_setprio(0);

#define TILE(T, BFC, BFN)                                                     \
    {                                                                         \
        const char* as = lds + (2 * ((T) & 1) + wr) * 16384;                  \
        if ((T) + 1 < NT) {                                                   \
            LOADB(BFN, (T) + 1);                                              \
            SA((T) + 1, 0); SA((T) + 1, 1);                                   \
        }                                                                     \
        RD2(afX, 0);                                                          \
        RD2(afY, 2);                                                          \
        LGKM(4); MB(afX, BFC, 0);                                             \
        RD2(afX, 4);                                                          \
        LGKM(4); MB(afY, BFC, 2);                                             \
        RD2(afY, 6);                                                          \
        LGKM(4); MB(afX, BFC, 4);                                             \
        LGKM(0); MB(afY, BFC, 6);                                             \
        asm volatile("s_waitcnt vmcnt(0)" ::: "memory");                      \
        __builtin_amdgcn_s_barrier();                                         \
        __builtin_amdgcn_sched_barrier(0);                                    \
    }

    for (int t = 0; t < NT; t += 2) {
        TILE(t,     bfA, bfB);
        TILE(t + 1, bfB, bfA);
    }
#undef TILE
#undef MB
#undef RD2
#undef LGKM
#undef LOADB

    // ---- fused epilogue: 4 gates lane-local ----
    const int st  = S0 + wc * 16 + l15;
    const float b_i = bx[st];
    const float b_f = bx[1024 + st];
    const float b_o = bx[2048 + st];
    const float b_g = bx[3072 + st];
    const int rbase = m0 + wr * 128 + (lane >> 4) * 4;

#pragma unroll
    for (int m = 0; m < 8; ++m) {
#pragma unroll
        for (int q = 0; q < 4; ++q) {
            int row = rbase + m * 16 + q;
            float ib = acc[m][0][q] + b_i;
            float fb = acc[m][1][q] + b_f;
            float ob = acc[m][2][q] + b_o;
            float gb = acc[m][3][q] + b_g;
            float ig = fast_sigmoid(ib);
            float fg = fast_sigmoid(fb);
            float og = fast_sigmoid(ob);
            float gg = fast_tanh(gb);
            float pc = prevc[(size_t)row * SDIM + st];
            float nc = pc * fg + gg * ig;
            float nh = fast_tanh(nc) * og;
            outh[(size_t)row * SDIM + st] = nh;
            outc[(size_t)row * SDIM + st] = nc;
        }
    }
}

extern "C" void kernel_launch(void* const* d_in, const int* in_sizes, int n_in,
                              void* d_out, int out_size, void* d_ws, size_t ws_size,
                              hipStream_t stream) {
    const float* x     = (const float*)d_in[0];
    const float* prevh = (const float*)d_in[1];
    const float* prevc = (const float*)d_in[2];
    const float* Wx    = (const float*)d_in[3];
    const float* bx    = (const float*)d_in[4];
    const float* Wh    = (const float*)d_in[5];

    __hip_bfloat16* Abf = (__hip_bfloat16*)d_ws;
    __hip_bfloat16* Wt2 = Abf + (size_t)BATCH * KDIM;   // +32MB

    float* outh = (float*)d_out;
    float* outc = outh + (size_t)BATCH * SDIM;

    hipLaunchKernelGGL(convA, dim3(8192), dim3(256), 0, stream, x, prevh, Abf);
    hipLaunchKernelGGL(convW2, dim3(4096), dim3(256), 0, stream, Wx, Wh, Wt2);
    hipLaunchKernelGGL(lstm_gemm, dim3(512), dim3(512), 0, stream,
                       Abf, Wt2, bx, prevc, outh, outc);
}